// Round 7
// baseline (240.625 us; speedup 1.0000x reference)
//
#include <hip/hip_runtime.h>

#define DIMN 1024
#define NH 16
#define DH 64
#define SXX 1024
#define SKV 2048

typedef __bf16 bf16x8 __attribute__((ext_vector_type(8)));
typedef float f32x4 __attribute__((ext_vector_type(4)));
typedef unsigned short us8 __attribute__((ext_vector_type(8)));

__device__ __forceinline__ unsigned short f2bs(float f) {  // round-half-up bf16
    return (unsigned short)((__builtin_bit_cast(unsigned int, f) + 0x8000u) >> 16);
}
__device__ __forceinline__ unsigned int pk2(float a, float b) {  // packed bf16x2, round-half-up
    return ((__builtin_bit_cast(unsigned int, a) + 0x8000u) >> 16)
         | ((__builtin_bit_cast(unsigned int, b) + 0x8000u) & 0xffff0000u);
}

// ---------------- fused fp32 -> bf16 convert (8 regions, 1 launch) ----------------
struct CvtArgs {
    const float* src[8];
    unsigned short* dst[8];
    int start[8];
};
__global__ __launch_bounds__(256) void cvt_all(CvtArgs a) {
    int b = blockIdx.x;
    int r = 0;
#pragma unroll
    for (int i = 1; i < 8; i++) r += (b >= a.start[i]);
    int off = ((b - a.start[r]) * 256 + (int)threadIdx.x) * 8;
    const float* s = a.src[r] + off;
    float4 f0 = *(const float4*)(s);
    float4 f1 = *(const float4*)(s + 4);
    us8 o;
    o[0] = f2bs(f0.x); o[1] = f2bs(f0.y); o[2] = f2bs(f0.z); o[3] = f2bs(f0.w);
    o[4] = f2bs(f1.x); o[5] = f2bs(f1.y); o[6] = f2bs(f1.z); o[7] = f2bs(f1.w);
    *(us8*)(a.dst[r] + off) = o;
}

// ---------------- GEMM core: 128x128 tile, BK=64, reg-prefetch + ds_write, 1 buffer ---
__device__ __forceinline__ void gemm_core(const unsigned short* __restrict__ A,
                                          const unsigned short* __restrict__ W,
                                          unsigned short* As, unsigned short* Bs,
                                          int m0, int n0, f32x4 (&acc)[4][4]) {
    const int K = DIMN;
    int tid = threadIdx.x, wave = tid >> 6, lane = tid & 63;
    int l15 = lane & 15, quad = lane >> 4;
    int wm = wave >> 1, wn = wave & 1;
    int srow = wave * 8 + (lane >> 3);
    int gcol = ((lane & 7) ^ (lane >> 3)) * 8;   // swizzled global column chunk
    const unsigned short* gA = A + (size_t)(m0 + srow) * K + gcol;
    const unsigned short* gW = W + (size_t)(n0 + srow) * K + gcol;
    int ldswr = wave * 512 + lane * 8;           // this lane's LDS chunk (shorts)
    int slot0 = (quad ^ (l15 & 7)) * 8;          // LDS slot for global chunk 'quad'

    us8 pa[4], pw[4];
    auto gload = [&](int k0) {
#pragma unroll
        for (int j = 0; j < 4; j++) {
            pa[j] = *(const us8*)(gA + k0 + (size_t)j * 32 * K);
            pw[j] = *(const us8*)(gW + k0 + (size_t)j * 32 * K);
        }
    };
    auto lwrite = [&]() {
#pragma unroll
        for (int j = 0; j < 4; j++) {
            *(us8*)(&As[ldswr + j * 2048]) = pa[j];
            *(us8*)(&Bs[ldswr + j * 2048]) = pw[j];
        }
    };

    gload(0);
    for (int k0 = 0; k0 < K; k0 += 64) {
        if (k0) __syncthreads();                 // prev compute done reading LDS
        lwrite();
        if (k0 + 64 < K) gload(k0 + 64);         // issue next tile's loads NOW
        __syncthreads();                         // LDS writes visible
#pragma unroll
        for (int kk = 0; kk < 2; kk++) {
            int sl = slot0 ^ (kk * 32);
            bf16x8 af[4], bf[4];
#pragma unroll
            for (int mi = 0; mi < 4; mi++)
                af[mi] = __builtin_bit_cast(bf16x8, *(const us8*)(&As[(wm * 64 + mi * 16 + l15) * 64 + sl]));
#pragma unroll
            for (int ni = 0; ni < 4; ni++)
                bf[ni] = __builtin_bit_cast(bf16x8, *(const us8*)(&Bs[(wn * 64 + ni * 16 + l15) * 64 + sl]));
#pragma unroll
            for (int mi = 0; mi < 4; mi++)
#pragma unroll
                for (int ni = 0; ni < 4; ni++)
                    acc[mi][ni] = __builtin_amdgcn_mfma_f32_16x16x32_bf16(af[mi], bf[ni], acc[mi][ni], 0, 0, 0);
        }
    }
}

// ---------------- merged projection GEMM: 1280 blocks ----------------
__global__ __launch_bounds__(256, 3) void gemm_proj(
        const unsigned short* __restrict__ xb, const unsigned short* __restrict__ yb,
        const unsigned short* __restrict__ Wb,
        const float* __restrict__ b_Kx, const float* __restrict__ b_Qx, const float* __restrict__ b_Ky,
        const float* __restrict__ b_Vx, const float* __restrict__ b_Vy,
        unsigned short* __restrict__ Qd, unsigned short* __restrict__ Kd,
        unsigned short* __restrict__ Vd, float qscale) {
    __shared__ __align__(16) unsigned short As[128 * 64];
    __shared__ __align__(16) unsigned short Bs[128 * 64];
    int bx = blockIdx.x;
    int tid = threadIdx.x, wave = tid >> 6, lane = tid & 63;
    int l15 = lane & 15, quad = lane >> 4;
    int wm = wave >> 1, wn = wave & 1;

    f32x4 acc[4][4] = {};

    if (bx < 768) {
        int sub = bx >> 8, t = bx & 255;
        int n0 = (t & 7) * 128, m0 = (t >> 3) * 128;
        const unsigned short* A = (sub == 2) ? yb : xb;
        const unsigned short* W = Wb + (size_t)((sub == 0) ? 0 : (sub == 1) ? 1 : 3) * 1048576;
        const float* bp = (sub == 0) ? b_Kx : (sub == 1) ? b_Qx : b_Ky;
        int roff = (sub == 2) ? 1024 : 0;
        float sc = (sub == 1) ? qscale : 1.0f;

        gemm_core(A, W, As, Bs, m0, n0, acc);

#pragma unroll
        for (int mi = 0; mi < 4; mi++) {
            int mbase = m0 + wm * 64 + mi * 16 + quad * 4;
#pragma unroll
            for (int ni = 0; ni < 4; ni++) {
                int n = n0 + wn * 64 + ni * 16 + l15;
                float bv = bp[n];
                int h = n >> 6, d = n & 63;
#pragma unroll
                for (int r = 0; r < 4; r++) {
                    float v = (acc[mi][ni][r] + bv) * sc;
                    int mm = mbase + r;
                    int bidx = mm >> 10, s = mm & 1023;
                    if (sub == 1)
                        Qd[((size_t)(bidx * NH + h) * SXX + s) * DH + d] = f2bs(v);
                    else
                        Kd[((size_t)(bidx * NH + h) * SKV + s + roff) * DH + d] = f2bs(v);
                }
            }
        }
    } else {
        int u = bx - 768;
        int side = u >> 8, t = u & 255;
        int m0 = (t & 7) * 128, n0 = (t >> 3) * 128;
        const unsigned short* Wv = Wb + (size_t)(side ? 4 : 2) * 1048576;
        const unsigned short* act = side ? yb : xb;
        const float* bp = side ? b_Vy : b_Vx;
        int roff = side ? 1024 : 0;

        gemm_core(Wv, act, As, Bs, m0, n0, acc);

#pragma unroll
        for (int mi = 0; mi < 4; mi++) {
            int mbase = m0 + wm * 64 + mi * 16 + quad * 4;
#pragma unroll
            for (int ni = 0; ni < 4; ni++) {
                int n = n0 + wn * 64 + ni * 16 + l15;
                int bidx = n >> 10, s = n & 1023;
#pragma unroll
                for (int r = 0; r < 4; r++) {
                    int m = mbase + r;
                    int h = m >> 6, d = m & 63;
                    float v = acc[mi][ni][r] + bp[m];
                    Vd[((size_t)(bidx * NH + h) * DH + d) * SKV + s + roff] = f2bs(v);
                }
            }
        }
    }
}

// ---------------- out-projection: 64x128 tiles, reg-prefetch, grid(8,64) ----------------
__global__ __launch_bounds__(256, 3) void gemm_out(
        const unsigned short* __restrict__ Ob, const unsigned short* __restrict__ Wo,
        const float* __restrict__ bo, float* __restrict__ outp) {
    __shared__ __align__(16) unsigned short As[64 * 64];
    __shared__ __align__(16) unsigned short Bs[128 * 64];
    const int K = DIMN;
    int tid = threadIdx.x, wave = tid >> 6, lane = tid & 63;
    int l15 = lane & 15, quad = lane >> 4;
    int wm = wave >> 1, wn = wave & 1;
    int n0 = blockIdx.x * 128, m0 = blockIdx.y * 64;

    int srow = wave * 8 + (lane >> 3);
    int gcol = ((lane & 7) ^ (lane >> 3)) * 8;
    const unsigned short* gA = Ob + (size_t)(m0 + srow) * K + gcol;
    const unsigned short* gW = Wo + (size_t)(n0 + srow) * K + gcol;
    int ldswr = wave * 512 + lane * 8;
    int slot0 = (quad ^ (l15 & 7)) * 8;

    us8 pa[2], pw[4];
    auto gload = [&](int k0) {
#pragma unroll
        for (int j = 0; j < 2; j++)
            pa[j] = *(const us8*)(gA + k0 + (size_t)j * 32 * K);
#pragma unroll
        for (int j = 0; j < 4; j++)
            pw[j] = *(const us8*)(gW + k0 + (size_t)j * 32 * K);
    };
    auto lwrite = [&]() {
#pragma unroll
        for (int j = 0; j < 2; j++)
            *(us8*)(&As[ldswr + j * 2048]) = pa[j];
#pragma unroll
        for (int j = 0; j < 4; j++)
            *(us8*)(&Bs[ldswr + j * 2048]) = pw[j];
    };

    f32x4 acc[2][4] = {};
    gload(0);
    for (int k0 = 0; k0 < K; k0 += 64) {
        if (k0) __syncthreads();
        lwrite();
        if (k0 + 64 < K) gload(k0 + 64);
        __syncthreads();
#pragma unroll
        for (int kk = 0; kk < 2; kk++) {
            int sl = slot0 ^ (kk * 32);
            bf16x8 af[2], bf[4];
#pragma unroll
            for (int mi = 0; mi < 2; mi++)
                af[mi] = __builtin_bit_cast(bf16x8, *(const us8*)(&As[(wm * 32 + mi * 16 + l15) * 64 + sl]));
#pragma unroll
            for (int ni = 0; ni < 4; ni++)
                bf[ni] = __builtin_bit_cast(bf16x8, *(const us8*)(&Bs[(wn * 64 + ni * 16 + l15) * 64 + sl]));
#pragma unroll
            for (int mi = 0; mi < 2; mi++)
#pragma unroll
                for (int ni = 0; ni < 4; ni++)
                    acc[mi][ni] = __builtin_amdgcn_mfma_f32_16x16x32_bf16(af[mi], bf[ni], acc[mi][ni], 0, 0, 0);
        }
    }

#pragma unroll
    for (int mi = 0; mi < 2; mi++) {
        int mbase = m0 + wm * 32 + mi * 16 + quad * 4;
#pragma unroll
        for (int ni = 0; ni < 4; ni++) {
            int n = n0 + wn * 64 + ni * 16 + l15;
            float bv = bo[n];
#pragma unroll
            for (int r = 0; r < 4; r++)
                outp[(size_t)(mbase + r) * DIMN + n] = acc[mi][ni][r] + bv;
        }
    }
}

// ---------------- flash attention: 2-wave blocks, q=32/wave, S^T, no-max, dbuf --------
// grid(64 bh, 16 qblk), 128 threads. 4 blocks/CU; 2-wave barriers avoid phase convoy.
__global__ __launch_bounds__(128, 2) void flash_attn(
        const unsigned short* __restrict__ Qb,
        const unsigned short* __restrict__ Kc,
        const unsigned short* __restrict__ Vt,
        unsigned short* __restrict__ Ob) {
    __shared__ __align__(16) unsigned short Ks[2][64 * 64];
    __shared__ __align__(16) unsigned short Vs[2][64 * 64];
    __shared__ __align__(16) unsigned short Ps[2][32 * 64];
    int tid = threadIdx.x, wave = tid >> 6, lane = tid & 63;
    int l15 = lane & 15, quad = lane >> 4;
    int bh = blockIdx.x;
    int qbase = blockIdx.y * 64 + wave * 32;

    const unsigned short* Qp = Qb + ((size_t)bh * SXX + qbase) * DH;
    bf16x8 bq[2][2];
#pragma unroll
    for (int qt = 0; qt < 2; qt++) {
        bq[qt][0] = __builtin_bit_cast(bf16x8, *(const us8*)(&Qp[(qt * 16 + l15) * DH + quad * 8]));
        bq[qt][1] = __builtin_bit_cast(bf16x8, *(const us8*)(&Qp[(qt * 16 + l15) * DH + 32 + quad * 8]));
    }

    const unsigned short* Kg = Kc + (size_t)bh * SKV * DH;
    const unsigned short* Vg = Vt + (size_t)bh * DH * SKV;

    // staging: 128 threads cover 64 rows x 8 chunks in 4 passes (rows tid>>3 + 16j)
    int srow = tid >> 3;                          // 0..15
    int swz = ((tid & 7) ^ (srow & 7)) * 8;       // swizzled global column for this slot
    int sl = (tid & 7) * 8;

    us8 pk[4], pv[4];
    auto gload = [&](int c) {
#pragma unroll
        for (int j = 0; j < 4; j++) {
            int r = srow + 16 * j;
            pk[j] = *(const us8*)(Kg + (size_t)(c + r) * DH + swz);
            pv[j] = *(const us8*)(Vg + (size_t)r * SKV + c + swz);
        }
    };
    auto lstore = [&](int buf) {
#pragma unroll
        for (int j = 0; j < 4; j++) {
            int r = srow + 16 * j;
            *(us8*)(&Ks[buf][r * 64 + sl]) = pk[j];
            *(us8*)(&Vs[buf][r * 64 + sl]) = pv[j];
        }
    };

    f32x4 o[2][4] = {};
    float lsum[2] = {0.f, 0.f};
    int cA = (quad ^ (l15 & 7)) * 8;

    gload(0);
    lstore(0);
    __syncthreads();

    for (int c = 0; c < SKV; c += 64) {
        int cur = (c >> 6) & 1;
        bool more = (c + 64) < SKV;
        if (more) gload(c + 64);

        const unsigned short* ks = &Ks[cur][0];
        bf16x8 ak0[4], ak1[4];
#pragma unroll
        for (int ni = 0; ni < 4; ni++) {
            int row = (ni * 16 + l15) * 64;
            ak0[ni] = __builtin_bit_cast(bf16x8, *(const us8*)(ks + row + cA));
            ak1[ni] = __builtin_bit_cast(bf16x8, *(const us8*)(ks + row + (cA ^ 32)));
        }

        unsigned short* pw = &Ps[wave][0];
#pragma unroll
        for (int qt = 0; qt < 2; qt++) {
#pragma unroll
            for (int ni = 0; ni < 4; ni++) {
                f32x4 z = {};
                z = __builtin_amdgcn_mfma_f32_16x16x32_bf16(ak0[ni], bq[qt][0], z, 0, 0, 0);
                z = __builtin_amdgcn_mfma_f32_16x16x32_bf16(ak1[ni], bq[qt][1], z, 0, 0, 0);
                float p0 = __builtin_amdgcn_exp2f(z[0]);
                float p1 = __builtin_amdgcn_exp2f(z[1]);
                float p2 = __builtin_amdgcn_exp2f(z[2]);
                float p3 = __builtin_amdgcn_exp2f(z[3]);
                lsum[qt] += (p0 + p1) + (p2 + p3);
                unsigned int lo = pk2(p0, p1);
                unsigned int hi = pk2(p2, p3);
                int c8p = (2 * ni + (quad >> 1)) ^ (l15 & 7);
                *(uint2*)(pw + (qt * 16 + l15) * 64 + c8p * 8 + (quad & 1) * 4) = make_uint2(lo, hi);
            }
        }

        const unsigned short* vs = &Vs[cur][0];
        bf16x8 av0[4], av1[4];
#pragma unroll
        for (int ni = 0; ni < 4; ni++) {
            int row = (ni * 16 + l15) * 64;
            av0[ni] = __builtin_bit_cast(bf16x8, *(const us8*)(vs + row + cA));
            av1[ni] = __builtin_bit_cast(bf16x8, *(const us8*)(vs + row + (cA ^ 32)));
        }
#pragma unroll
        for (int qt = 0; qt < 2; qt++) {
            bf16x8 ap0 = __builtin_bit_cast(bf16x8, *(const us8*)(pw + (qt * 16 + l15) * 64 + cA));
            bf16x8 ap1 = __builtin_bit_cast(bf16x8, *(const us8*)(pw + (qt * 16 + l15) * 64 + (cA ^ 32)));
#pragma unroll
            for (int ni = 0; ni < 4; ni++) {
                o[qt][ni] = __builtin_amdgcn_mfma_f32_16x16x32_bf16(ap0, av0[ni], o[qt][ni], 0, 0, 0);
                o[qt][ni] = __builtin_amdgcn_mfma_f32_16x16x32_bf16(ap1, av1[ni], o[qt][ni], 0, 0, 0);
            }
        }

        if (more) lstore(1 - cur);
        __syncthreads();
    }

    int b = bh >> 4, h = bh & 15;
#pragma unroll
    for (int qt = 0; qt < 2; qt++) {
        float ls = lsum[qt];
        ls += __shfl_xor(ls, 16);
        ls += __shfl_xor(ls, 32);
#pragma unroll
        for (int r = 0; r < 4; r++) {
            float lt = __shfl(ls, quad * 4 + r);
            float inv = __builtin_amdgcn_rcpf(lt);
            int q = qbase + qt * 16 + quad * 4 + r;
#pragma unroll
            for (int ni = 0; ni < 4; ni++)
                Ob[((size_t)b * SXX + q) * DIMN + h * DH + ni * 16 + l15] = f2bs(o[qt][ni][r] * inv);
        }
    }
}

extern "C" void kernel_launch(void* const* d_in, const int* in_sizes, int n_in,
                              void* d_out, int out_size, void* d_ws, size_t ws_size,
                              hipStream_t stream) {
    (void)in_sizes; (void)n_in; (void)out_size; (void)ws_size;
    const float* x     = (const float*)d_in[0];
    const float* y     = (const float*)d_in[1];
    const float* W_Kx  = (const float*)d_in[2];
    const float* b_Kx  = (const float*)d_in[3];
    const float* W_Qx  = (const float*)d_in[4];
    const float* b_Qx  = (const float*)d_in[5];
    const float* W_Vx  = (const float*)d_in[6];
    const float* b_Vx  = (const float*)d_in[7];
    const float* W_Ky  = (const float*)d_in[8];
    const float* b_Ky  = (const float*)d_in[9];
    const float* W_Vy  = (const float*)d_in[10];
    const float* b_Vy  = (const float*)d_in[11];
    const float* W_out = (const float*)d_in[12];
    const float* b_out = (const float*)d_in[13];
    float* out = (float*)d_out;

    char* ws = (char*)d_ws;
    unsigned short* xb  = (unsigned short*)(ws);                       // 8 MB
    unsigned short* yb  = (unsigned short*)(ws + (size_t)( 8 << 20));  // 8 MB
    unsigned short* Qb  = (unsigned short*)(ws + (size_t)(16 << 20));  // 8 MB
    unsigned short* Kcw = (unsigned short*)(ws + (size_t)(24 << 20));  // 16 MB
    unsigned short* Vtw = (unsigned short*)(ws + (size_t)(40 << 20));  // 16 MB
    unsigned short* Obw = (unsigned short*)(ws + (size_t)(56 << 20));  // 8 MB
    unsigned short* Wb  = (unsigned short*)(ws + (size_t)(64 << 20));  // [Kx][Qx][Vx][Ky][Vy][out]

    CvtArgs ca;
    ca.src[0] = x;     ca.dst[0] = xb;                 ca.start[0] = 0;
    ca.src[1] = y;     ca.dst[1] = yb;                 ca.start[1] = 2048;
    ca.src[2] = W_Kx;  ca.dst[2] = Wb + 0u * 1048576;  ca.start[2] = 4096;
    ca.src[3] = W_Qx;  ca.dst[3] = Wb + 1u * 1048576;  ca.start[3] = 4608;
    ca.src[4] = W_Vx;  ca.dst[4] = Wb + 2u * 1048576;  ca.start[4] = 5120;
    ca.src[5] = W_Ky;  ca.dst[5] = Wb + 3u * 1048576;  ca.start[5] = 5632;
    ca.src[6] = W_Vy;  ca.dst[6] = Wb + 4u * 1048576;  ca.start[6] = 6144;
    ca.src[7] = W_out; ca.dst[7] = Wb + 5u * 1048576;  ca.start[7] = 6656;
    cvt_all<<<7168, 256, 0, stream>>>(ca);

    const float qscale = 0.125f * 1.44269504088896340736f;  // 1/sqrt(Dh) * log2(e)
    gemm_proj<<<1280, 256, 0, stream>>>(xb, yb, Wb, b_Kx, b_Qx, b_Ky, b_Vx, b_Vy,
                                        Qb, Kcw, Vtw, qscale);
    flash_attn<<<dim3(64, 16), 128, 0, stream>>>(Qb, Kcw, Vtw, Obw);
    gemm_out<<<dim3(8, 64), 256, 0, stream>>>(Obw, Wb + 5u * 1048576, b_out, out);
}